// Round 1
// baseline (4116.253 us; speedup 1.0000x reference)
//
#include <hip/hip_runtime.h>
#include <math.h>

namespace {

constexpr int Bb = 16;
constexpr int TQ = 2048;
constexpr int TK = 2048;
constexpr int D  = 1024;

constexpr int BM = 128, BN = 128, BK = 16;

// ---------------------------------------------------------------------------
// NN GEMM: C[m][n] = sum_k A[m][k] * B[k][n]  (+ optional bias[n])
// 128x128 tile, BK=16, 256 threads, 8x8 micro-tile per thread.
// Batched via z-dim with element strides sA/sB/sC (sB==0 -> shared B).
// ---------------------------------------------------------------------------
__global__ __launch_bounds__(256)
void gemm_nn_kernel(const float* __restrict__ A, const float* __restrict__ Bm,
                    const float* __restrict__ bias, float* __restrict__ C,
                    int M, int N, int K,
                    long long sA, long long sB, long long sC)
{
    __shared__ float As[BK][BM];
    __shared__ float Bs[BK][BN];

    const int bz = blockIdx.z;
    const int n0 = blockIdx.x * BN;
    const int m0 = blockIdx.y * BM;
    const float* Ab = A  + (long long)bz * sA;
    const float* Bp = Bm + (long long)bz * sB;
    float*       Cb = C  + (long long)bz * sC;

    const int tid = threadIdx.x;
    const int tx = tid & 15;   // n direction
    const int ty = tid >> 4;   // m direction

    float acc[8][8];
    #pragma unroll
    for (int i = 0; i < 8; ++i)
        #pragma unroll
        for (int j = 0; j < 8; ++j) acc[i][j] = 0.f;

    for (int k0 = 0; k0 < K; k0 += BK) {
        // A tile: BM x BK, transpose into As[k][m]
        #pragma unroll
        for (int i = 0; i < 2; ++i) {
            int idx = tid * 2 + i;          // 0..511 (4 float4 per row)
            int row = idx >> 2;
            int c4  = idx & 3;
            float4 v = *(const float4*)(Ab + (long long)(m0 + row) * K + k0 + c4 * 4);
            As[c4 * 4 + 0][row] = v.x;
            As[c4 * 4 + 1][row] = v.y;
            As[c4 * 4 + 2][row] = v.z;
            As[c4 * 4 + 3][row] = v.w;
        }
        // B tile: BK x BN, direct into Bs[k][n]
        #pragma unroll
        for (int i = 0; i < 2; ++i) {
            int idx = tid * 2 + i;          // 0..511 (32 float4 per row)
            int row = idx >> 5;
            int c4  = idx & 31;
            float4 v = *(const float4*)(Bp + (long long)(k0 + row) * N + n0 + c4 * 4);
            *(float4*)&Bs[row][c4 * 4] = v;
        }
        __syncthreads();

        #pragma unroll
        for (int kk = 0; kk < BK; ++kk) {
            float a[8], b[8];
            *(float4*)&a[0] = *(const float4*)&As[kk][ty * 8];
            *(float4*)&a[4] = *(const float4*)&As[kk][ty * 8 + 4];
            *(float4*)&b[0] = *(const float4*)&Bs[kk][tx * 8];
            *(float4*)&b[4] = *(const float4*)&Bs[kk][tx * 8 + 4];
            #pragma unroll
            for (int i = 0; i < 8; ++i)
                #pragma unroll
                for (int j = 0; j < 8; ++j)
                    acc[i][j] = fmaf(a[i], b[j], acc[i][j]);
        }
        __syncthreads();
    }

    #pragma unroll
    for (int i = 0; i < 8; ++i) {
        int m = m0 + ty * 8 + i;
        #pragma unroll
        for (int jv = 0; jv < 2; ++jv) {
            int n = n0 + tx * 8 + jv * 4;
            float4 v;
            v.x = acc[i][jv * 4 + 0];
            v.y = acc[i][jv * 4 + 1];
            v.z = acc[i][jv * 4 + 2];
            v.w = acc[i][jv * 4 + 3];
            if (bias) {
                v.x += bias[n + 0]; v.y += bias[n + 1];
                v.z += bias[n + 2]; v.w += bias[n + 3];
            }
            *(float4*)(Cb + (long long)m * N + n) = v;
        }
    }
}

// ---------------------------------------------------------------------------
// NT GEMM: C[m][n] = sum_k A[m][k] * B[n][k]   (both row-major over k)
// ---------------------------------------------------------------------------
__global__ __launch_bounds__(256)
void gemm_nt_kernel(const float* __restrict__ A, const float* __restrict__ Bm,
                    float* __restrict__ C,
                    int M, int N, int K,
                    long long sA, long long sB, long long sC)
{
    __shared__ float As[BK][BM];
    __shared__ float Bs[BK][BN];

    const int bz = blockIdx.z;
    const int n0 = blockIdx.x * BN;
    const int m0 = blockIdx.y * BM;
    const float* Ab = A  + (long long)bz * sA;
    const float* Bp = Bm + (long long)bz * sB;
    float*       Cb = C  + (long long)bz * sC;

    const int tid = threadIdx.x;
    const int tx = tid & 15;
    const int ty = tid >> 4;

    float acc[8][8];
    #pragma unroll
    for (int i = 0; i < 8; ++i)
        #pragma unroll
        for (int j = 0; j < 8; ++j) acc[i][j] = 0.f;

    for (int k0 = 0; k0 < K; k0 += BK) {
        #pragma unroll
        for (int i = 0; i < 2; ++i) {
            int idx = tid * 2 + i;
            int row = idx >> 2;
            int c4  = idx & 3;
            float4 v = *(const float4*)(Ab + (long long)(m0 + row) * K + k0 + c4 * 4);
            As[c4 * 4 + 0][row] = v.x;
            As[c4 * 4 + 1][row] = v.y;
            As[c4 * 4 + 2][row] = v.z;
            As[c4 * 4 + 3][row] = v.w;
        }
        #pragma unroll
        for (int i = 0; i < 2; ++i) {
            int idx = tid * 2 + i;
            int row = idx >> 2;
            int c4  = idx & 3;
            float4 v = *(const float4*)(Bp + (long long)(n0 + row) * K + k0 + c4 * 4);
            Bs[c4 * 4 + 0][row] = v.x;
            Bs[c4 * 4 + 1][row] = v.y;
            Bs[c4 * 4 + 2][row] = v.z;
            Bs[c4 * 4 + 3][row] = v.w;
        }
        __syncthreads();

        #pragma unroll
        for (int kk = 0; kk < BK; ++kk) {
            float a[8], b[8];
            *(float4*)&a[0] = *(const float4*)&As[kk][ty * 8];
            *(float4*)&a[4] = *(const float4*)&As[kk][ty * 8 + 4];
            *(float4*)&b[0] = *(const float4*)&Bs[kk][tx * 8];
            *(float4*)&b[4] = *(const float4*)&Bs[kk][tx * 8 + 4];
            #pragma unroll
            for (int i = 0; i < 8; ++i)
                #pragma unroll
                for (int j = 0; j < 8; ++j)
                    acc[i][j] = fmaf(a[i], b[j], acc[i][j]);
        }
        __syncthreads();
    }

    #pragma unroll
    for (int i = 0; i < 8; ++i) {
        int m = m0 + ty * 8 + i;
        #pragma unroll
        for (int jv = 0; jv < 2; ++jv) {
            int n = n0 + tx * 8 + jv * 4;
            float4 v;
            v.x = acc[i][jv * 4 + 0];
            v.y = acc[i][jv * 4 + 1];
            v.z = acc[i][jv * 4 + 2];
            v.w = acc[i][jv * 4 + 3];
            *(float4*)(Cb + (long long)m * N + n) = v;
        }
    }
}

// ---------------------------------------------------------------------------
// Row softmax in place: one block per row of TK=2048 floats, 256 thr x 8 elem
// ---------------------------------------------------------------------------
__global__ __launch_bounds__(256)
void softmax_kernel(float* __restrict__ S)
{
    __shared__ float red[4];
    const long long row = blockIdx.x;
    float* p = S + row * (long long)TK;
    const int tid = threadIdx.x;

    float x[8];
    *(float4*)&x[0] = *(const float4*)(p + tid * 8);
    *(float4*)&x[4] = *(const float4*)(p + tid * 8 + 4);

    float mx = x[0];
    #pragma unroll
    for (int i = 1; i < 8; ++i) mx = fmaxf(mx, x[i]);
    #pragma unroll
    for (int off = 32; off > 0; off >>= 1) mx = fmaxf(mx, __shfl_down(mx, off, 64));
    if ((tid & 63) == 0) red[tid >> 6] = mx;
    __syncthreads();
    mx = fmaxf(fmaxf(red[0], red[1]), fmaxf(red[2], red[3]));
    __syncthreads();

    float s = 0.f;
    #pragma unroll
    for (int i = 0; i < 8; ++i) { x[i] = __expf(x[i] - mx); s += x[i]; }
    #pragma unroll
    for (int off = 32; off > 0; off >>= 1) s += __shfl_down(s, off, 64);
    if ((tid & 63) == 0) red[tid >> 6] = s;
    __syncthreads();
    s = red[0] + red[1] + red[2] + red[3];

    float inv = 1.f / s;
    #pragma unroll
    for (int i = 0; i < 8; ++i) x[i] *= inv;
    *(float4*)(p + tid * 8)     = *(const float4*)&x[0];
    *(float4*)(p + tid * 8 + 4) = *(const float4*)&x[4];
}

} // anonymous namespace

extern "C" void kernel_launch(void* const* d_in, const int* in_sizes, int n_in,
                              void* d_out, int out_size, void* d_ws, size_t ws_size,
                              hipStream_t stream)
{
    const float* dec  = (const float*)d_in[0];  // [B, TQ, D]
    const float* enc  = (const float*)d_in[1];  // [B, TK, D]
    const float* W    = (const float*)d_in[2];  // [D, D]
    const float* bias = (const float*)d_in[3];  // [D]

    float* out     = (float*)d_out;
    float* context = out;                                // [B, TQ, D]
    float* align   = out + (long long)Bb * TQ * D;       // [B, TQ, TK]
    float* keys    = (float*)d_ws;                       // [B, TK, D] fp32 (134 MB)

    dim3 blk(256);

    // 1) keys = enc @ W + bias            [B, TK, D]
    gemm_nn_kernel<<<dim3(D / BN, TK / BM, Bb), blk, 0, stream>>>(
        enc, W, bias, keys, TK, D, D,
        (long long)TK * D, 0LL, (long long)TK * D);

    // 2) score = dec @ keys^T  -> written into alignment region of d_out
    gemm_nt_kernel<<<dim3(TK / BN, TQ / BM, Bb), blk, 0, stream>>>(
        dec, keys, align, TQ, TK, D,
        (long long)TQ * D, (long long)TK * D, (long long)TQ * TK);

    // 3) softmax over k axis, in place
    softmax_kernel<<<dim3(Bb * TQ), blk, 0, stream>>>(align);

    // 4) context = align @ enc            [B, TQ, D]
    gemm_nn_kernel<<<dim3(D / BN, TQ / BM, Bb), blk, 0, stream>>>(
        align, enc, nullptr, context, TQ, D, TK,
        (long long)TQ * TK, (long long)TK * D, (long long)TQ * D);
}

// Round 2
// 1658.650 us; speedup vs baseline: 2.4817x; 2.4817x over previous
//
#include <hip/hip_runtime.h>
#include <math.h>

namespace {

constexpr int Bb = 16;
constexpr int TQ = 2048;
constexpr int TK = 2048;
constexpr int D  = 1024;

constexpr int BM = 128, BN = 128, BK = 32;

typedef __bf16 bf16x8 __attribute__((ext_vector_type(8)));
typedef float  f32x4  __attribute__((ext_vector_type(4)));

__device__ inline unsigned short f2bf(float f) {
    unsigned u = __builtin_bit_cast(unsigned, f);
    u += 0x7fffu + ((u >> 16) & 1u);          // round-to-nearest-even
    return (unsigned short)(u >> 16);
}
__device__ inline float bf2f(unsigned short h) {
    unsigned u = (unsigned)h << 16;
    return __builtin_bit_cast(float, u);
}
__device__ inline void split1(float f, unsigned short& h, unsigned short& l) {
    h = f2bf(f);
    l = f2bf(f - bf2f(h));
}

// ---------------------------------------------------------------------------
// NT GEMM via MFMA: C[m][n] = sum_k A[m][k] * Bt[n][k]
//   A : fp32 [M][K] row-major (split to bf16 hi/lo on the fly)
//   Bt: bf16 [N][K] row-major (pre-split hi/lo if NPROD==3)
// NPROD==3: bf16x3 product (hh + hl + lh). NPROD==1: plain bf16 (hi only).
// EPI==0: store fp32 C. EPI==1: add bias[n], store split bf16 (Ch, Cl).
// 128x128 tile, BK=32, 256 thr = 4 waves, each wave 4x4 tiles of 16x16x32.
// ---------------------------------------------------------------------------
template<int NPROD, int EPI>
__global__ __launch_bounds__(256)
void gemm_nt_mfma(const float* __restrict__ A,
                  const unsigned short* __restrict__ B0,
                  const unsigned short* __restrict__ B1,
                  const float* __restrict__ bias,
                  float* __restrict__ Cf,
                  unsigned short* __restrict__ Ch,
                  unsigned short* __restrict__ Cl,
                  int M, int N, int K,
                  long long sA, long long sB, long long sC)
{
    __shared__ unsigned short Ah[BM * BK];
    __shared__ unsigned short Al[NPROD == 3 ? BM * BK : 1];
    __shared__ unsigned short Bh[BN * BK];
    __shared__ unsigned short Bl[NPROD == 3 ? BN * BK : 1];

    const int bz = blockIdx.z;
    const int n0 = blockIdx.x * BN;
    const int m0 = blockIdx.y * BM;
    const float*          Ab  = A  + (long long)bz * sA;
    const unsigned short* B0b = B0 + (long long)bz * sB;
    const unsigned short* B1b = (NPROD == 3) ? (B1 + (long long)bz * sB) : nullptr;

    const int tid  = threadIdx.x;
    const int lane = tid & 63;
    const int wave = tid >> 6;
    const int wm = (wave >> 1) * 64;   // wave row offset within 128-tile
    const int wn = (wave & 1) * 64;    // wave col offset
    const int lr = lane & 15;
    const int lq = lane >> 4;

    f32x4 acc[4][4];
    #pragma unroll
    for (int i = 0; i < 4; ++i)
        #pragma unroll
        for (int j = 0; j < 4; ++j)
            acc[i][j] = (f32x4){0.f, 0.f, 0.f, 0.f};

    for (int k0 = 0; k0 < K; k0 += BK) {
        // ---- stage A: 128x32 fp32 -> bf16 hi(/lo) in LDS [row][k] ----
        #pragma unroll
        for (int i = 0; i < 4; ++i) {
            int c   = i * 256 + tid;       // 1024 float4 chunks
            int row = c >> 3;
            int q4  = c & 7;
            float4 v = *(const float4*)(Ab + (long long)(m0 + row) * K + k0 + q4 * 4);
            ushort4 h, l;
            if constexpr (NPROD == 3) {
                split1(v.x, h.x, l.x); split1(v.y, h.y, l.y);
                split1(v.z, h.z, l.z); split1(v.w, h.w, l.w);
            } else {
                h.x = f2bf(v.x); h.y = f2bf(v.y); h.z = f2bf(v.z); h.w = f2bf(v.w);
            }
            *(ushort4*)&Ah[row * BK + q4 * 4] = h;
            if constexpr (NPROD == 3)
                *(ushort4*)&Al[row * BK + q4 * 4] = l;
        }
        // ---- stage B: 128x32 bf16 -> LDS [row][k] ----
        #pragma unroll
        for (int i = 0; i < 2; ++i) {
            int c   = i * 256 + tid;       // 512 chunks of 8 bf16 (16 B)
            int row = c >> 2;
            int q   = c & 3;
            *(int4*)&Bh[row * BK + q * 8] =
                *(const int4*)(B0b + (long long)(n0 + row) * K + k0 + q * 8);
            if constexpr (NPROD == 3)
                *(int4*)&Bl[row * BK + q * 8] =
                    *(const int4*)(B1b + (long long)(n0 + row) * K + k0 + q * 8);
        }
        __syncthreads();

        // ---- fragments + MFMA ----
        bf16x8 afh[4], afl[4], bfh[4], bfl[4];
        #pragma unroll
        for (int mt = 0; mt < 4; ++mt) {
            afh[mt] = *(const bf16x8*)&Ah[(wm + mt * 16 + lr) * BK + lq * 8];
            if constexpr (NPROD == 3)
                afl[mt] = *(const bf16x8*)&Al[(wm + mt * 16 + lr) * BK + lq * 8];
        }
        #pragma unroll
        for (int nt = 0; nt < 4; ++nt) {
            bfh[nt] = *(const bf16x8*)&Bh[(wn + nt * 16 + lr) * BK + lq * 8];
            if constexpr (NPROD == 3)
                bfl[nt] = *(const bf16x8*)&Bl[(wn + nt * 16 + lr) * BK + lq * 8];
        }
        #pragma unroll
        for (int mt = 0; mt < 4; ++mt)
            #pragma unroll
            for (int nt = 0; nt < 4; ++nt) {
                acc[mt][nt] = __builtin_amdgcn_mfma_f32_16x16x32_bf16(
                    afh[mt], bfh[nt], acc[mt][nt], 0, 0, 0);
                if constexpr (NPROD == 3) {
                    acc[mt][nt] = __builtin_amdgcn_mfma_f32_16x16x32_bf16(
                        afh[mt], bfl[nt], acc[mt][nt], 0, 0, 0);
                    acc[mt][nt] = __builtin_amdgcn_mfma_f32_16x16x32_bf16(
                        afl[mt], bfh[nt], acc[mt][nt], 0, 0, 0);
                }
            }
        __syncthreads();
    }

    // ---- epilogue: C/D layout row=(lane>>4)*4+reg, col=lane&15 ----
    if constexpr (EPI == 0) {
        #pragma unroll
        for (int mt = 0; mt < 4; ++mt)
            #pragma unroll
            for (int nt = 0; nt < 4; ++nt) {
                int col = n0 + wn + nt * 16 + lr;
                #pragma unroll
                for (int rg = 0; rg < 4; ++rg) {
                    int row = m0 + wm + mt * 16 + lq * 4 + rg;
                    Cf[(long long)bz * sC + (long long)row * N + col] = acc[mt][nt][rg];
                }
            }
    } else {
        #pragma unroll
        for (int mt = 0; mt < 4; ++mt)
            #pragma unroll
            for (int nt = 0; nt < 4; ++nt) {
                int col = n0 + wn + nt * 16 + lr;
                float bv = bias[col];
                #pragma unroll
                for (int rg = 0; rg < 4; ++rg) {
                    int row = m0 + wm + mt * 16 + lq * 4 + rg;
                    long long off = (long long)bz * sC + (long long)row * N + col;
                    float v = acc[mt][nt][rg] + bv;
                    unsigned short h, l;
                    split1(v, h, l);
                    Ch[off] = h;
                    Cl[off] = l;
                }
            }
    }
}

// ---------------------------------------------------------------------------
// Transpose fp32 [R][C] -> bf16 [C][R] (hi, and lo if SPLIT). 32x32 tiles.
// ---------------------------------------------------------------------------
template<int SPLIT>
__global__ __launch_bounds__(256)
void transpose_bf16(const float* __restrict__ in,
                    unsigned short* __restrict__ outh,
                    unsigned short* __restrict__ outl,
                    int R, int C, long long sIn, long long sOut)
{
    __shared__ float t[32][33];
    const int bz = blockIdx.z;
    const int c0 = blockIdx.x * 32;
    const int r0 = blockIdx.y * 32;
    const float* inb = in + (long long)bz * sIn;
    const int tid = threadIdx.x;

    #pragma unroll
    for (int i = 0; i < 4; ++i) {
        int e = i * 256 + tid;
        int r = e >> 5, c = e & 31;
        t[r][c] = inb[(long long)(r0 + r) * C + c0 + c];
    }
    __syncthreads();
    #pragma unroll
    for (int i = 0; i < 4; ++i) {
        int e = i * 256 + tid;
        int r = e >> 5, c = e & 31;     // out coords: out[c0+r][r0+c]
        float v = t[c][r];
        long long off = (long long)bz * sOut + (long long)(c0 + r) * R + r0 + c;
        if constexpr (SPLIT) {
            unsigned short h, l;
            split1(v, h, l);
            outh[off] = h;
            outl[off] = l;
        } else {
            outh[off] = f2bf(v);
        }
    }
}

// ---------------------------------------------------------------------------
// Row softmax in place: one block per row of TK floats, 256 thr x 8 elems
// ---------------------------------------------------------------------------
__global__ __launch_bounds__(256)
void softmax_kernel(float* __restrict__ S)
{
    __shared__ float red[4];
    const long long row = blockIdx.x;
    float* p = S + row * (long long)TK;
    const int tid = threadIdx.x;

    float x[8];
    *(float4*)&x[0] = *(const float4*)(p + tid * 8);
    *(float4*)&x[4] = *(const float4*)(p + tid * 8 + 4);

    float mx = x[0];
    #pragma unroll
    for (int i = 1; i < 8; ++i) mx = fmaxf(mx, x[i]);
    #pragma unroll
    for (int off = 32; off > 0; off >>= 1) mx = fmaxf(mx, __shfl_down(mx, off, 64));
    if ((tid & 63) == 0) red[tid >> 6] = mx;
    __syncthreads();
    mx = fmaxf(fmaxf(red[0], red[1]), fmaxf(red[2], red[3]));
    __syncthreads();

    float s = 0.f;
    #pragma unroll
    for (int i = 0; i < 8; ++i) { x[i] = __expf(x[i] - mx); s += x[i]; }
    #pragma unroll
    for (int off = 32; off > 0; off >>= 1) s += __shfl_down(s, off, 64);
    if ((tid & 63) == 0) red[tid >> 6] = s;
    __syncthreads();
    s = red[0] + red[1] + red[2] + red[3];

    float inv = 1.f / s;
    #pragma unroll
    for (int i = 0; i < 8; ++i) x[i] *= inv;
    *(float4*)(p + tid * 8)     = *(const float4*)&x[0];
    *(float4*)(p + tid * 8 + 4) = *(const float4*)&x[4];
}

} // anonymous namespace

extern "C" void kernel_launch(void* const* d_in, const int* in_sizes, int n_in,
                              void* d_out, int out_size, void* d_ws, size_t ws_size,
                              hipStream_t stream)
{
    typedef long long ll;
    const float* dec  = (const float*)d_in[0];  // [B, TQ, D]
    const float* enc  = (const float*)d_in[1];  // [B, TK, D]
    const float* W    = (const float*)d_in[2];  // [D, D]
    const float* bias = (const float*)d_in[3];  // [D]

    float* out     = (float*)d_out;
    float* context = out;                               // [B, TQ, D]
    float* align   = out + (ll)Bb * TQ * D;             // [B, TQ, TK]

    // workspace layout (ushorts): keys_h, keys_l [B*TK*D], encT [B*D*TK], Wt_h, Wt_l [D*D]
    unsigned short* keys_h = (unsigned short*)d_ws;
    unsigned short* keys_l = keys_h + (ll)Bb * TK * D;
    unsigned short* encT   = keys_l + (ll)Bb * TK * D;
    unsigned short* Wt_h   = encT   + (ll)Bb * D * TK;
    unsigned short* Wt_l   = Wt_h   + (ll)D * D;

    dim3 blk(256);

    // 1) Wt = W^T split to bf16 hi/lo   [D][D]
    transpose_bf16<1><<<dim3(D / 32, D / 32, 1), blk, 0, stream>>>(
        W, Wt_h, Wt_l, D, D, 0LL, 0LL);

    // 2) encT = enc^T per batch, bf16   [B][D][TK]
    transpose_bf16<0><<<dim3(D / 32, TK / 32, Bb), blk, 0, stream>>>(
        enc, encT, nullptr, TK, D, (ll)TK * D, (ll)D * TK);

    // 3) keys = enc @ W + bias  (bf16x3), stored split bf16  [B][TK][D]
    gemm_nt_mfma<3, 1><<<dim3(D / BN, TK / BM, Bb), blk, 0, stream>>>(
        enc, Wt_h, Wt_l, bias, nullptr, keys_h, keys_l,
        TK, D, D, (ll)TK * D, 0LL, (ll)TK * D);

    // 4) score = dec @ keys^T  (bf16x3), fp32 -> align region
    gemm_nt_mfma<3, 0><<<dim3(TK / BN, TQ / BM, Bb), blk, 0, stream>>>(
        dec, keys_h, keys_l, nullptr, align, nullptr, nullptr,
        TQ, TK, D, (ll)TQ * D, (ll)TK * D, (ll)TQ * TK);

    // 5) softmax over k axis, in place
    softmax_kernel<<<dim3(Bb * TQ), blk, 0, stream>>>(align);

    // 6) context = align @ enc  (plain bf16 via encT)
    gemm_nt_mfma<1, 0><<<dim3(D / BN, TQ / BM, Bb), blk, 0, stream>>>(
        align, encT, nullptr, nullptr, context, nullptr, nullptr,
        TQ, D, TK, (ll)TQ * TK, (ll)D * TK, (ll)TQ * D);
}